// Round 8
// baseline (70.977 us; speedup 1.0000x reference)
//
#include <hip/hip_runtime.h>
#include <cstdint>
#include <cstddef>

// Problem constants
#define BB 64
#define TN 4096
#define FF 128
#define SPLIT 16                 // chunks per batch -> 1024 blocks, 4/CU
#define NBLK (BB * SPLIT)        // 1024
#define CHUNK (TN / SPLIT)       // 256
#define KT 64                    // t-rows per tile
#define NKT (CHUNK / KT)         // 4 phases
#define TSTRIDE 144              // bytes per f-row: 128 data + 16 pad (16B-aligned)

#define NTILE_UP 36              // upper-triangular 16x16 tiles of 128x128
#define TILE_ELEMS 256
#define PART_FLOATS (NTILE_UP * TILE_ELEMS)   // 9216 per block partial

// d_ws layout (floats): small atomic region first (memset'd), then big arrays
#define SUM0_OFF 0
#define MEAN_OFF (SUM0_OFF + BB * FF)
#define RSTD_OFF (MEAN_OFF + BB * FF)
#define SABS_OFF (RSTD_OFF + BB * FF)
#define TRI_OFF  (SABS_OFF + 1)
#define ZERO_FLOATS (TRI_OFF + 1)
#define R_OFF    24832                        // reduced S2 tiles: [BB][9216]
#define P_OFF    (R_OFF + BB * PART_FLOATS)   // partials: [NBLK][9216]

typedef __attribute__((ext_vector_type(8))) short bf16x8_t;
typedef __attribute__((ext_vector_type(4))) float f32x4;

__device__ __constant__ int kRowBase[8] = {0, 8, 15, 21, 26, 30, 33, 35};
// 36 upper-tri tiles split 9 per wave (4 waves): row, col, flat tile index
__device__ __constant__ uint8_t TR[4][9] = {
    {0,0,0,0,0,0,0,0,4},{1,1,1,1,1,1,1,4,4},{2,2,2,2,2,2,4,5,5},{3,3,3,3,3,5,6,6,7}};
__device__ __constant__ uint8_t TC[4][9] = {
    {0,1,2,3,4,5,6,7,4},{1,2,3,4,5,6,7,5,6},{2,3,4,5,6,7,7,5,6},{3,4,5,6,7,7,6,7,7}};
__device__ __constant__ uint8_t TT[4][9] = {
    {0,1,2,3,4,5,6,7,26},{8,9,10,11,12,13,14,27,28},
    {15,16,17,18,19,20,29,30,31},{21,22,23,24,25,32,33,34,35}};

static __device__ __forceinline__ unsigned f2bf(float f) {
    unsigned u = __builtin_bit_cast(unsigned, f);
    return (u + 0x7FFFu + ((u >> 16) & 1u)) >> 16;   // RNE
}
static __device__ __forceinline__ float elem(const float4& v, int j) {
    return reinterpret_cast<const float*>(&v)[j];    // j is compile-time after unroll
}

// ---------------------------------------------------------------------------
// Kernel 1: reg-staged bf16-MFMA syrk + fused transpose-convert + column sums.
// 1024 blocks x 256 thr (4 waves), 4 blocks/CU (16 waves/CU).
// Phase p: asm-issue 8 global_load_dwordx4 for tile p+1; MFMA on bufT[p&1];
//          vmcnt(0) + sched_barrier(0); convert+ds_write_b128 -> bufT[(p+1)&1];
//          lgkmcnt(0); one barrier.
// ---------------------------------------------------------------------------
__global__ __launch_bounds__(256, 4) void cov_kernel(const float* __restrict__ x,
                                                     float* __restrict__ ws)
{
    __shared__ __align__(16) char bufT[2][FF * TSTRIDE];   // 2 x 18 KiB bf16^T
    __shared__ float csr[4][FF];
    __shared__ float redsa[4];

    const int b = blockIdx.x >> 4;
    const int s = blockIdx.x & 15;
    const float* xb = x + ((size_t)b * TN + (size_t)s * CHUNK) * FF;

    const int tid  = threadIdx.x;
    const int w    = tid >> 6;     // wave 0..3
    const int lane = tid & 63;
    const int m    = lane & 15;    // MFMA frag coords
    const int h    = lane >> 4;    // 0..3
    const int c    = tid & 31;     // staging: f-quad (f = 4c..4c+3)
    const int rr   = tid >> 5;     // staging: 0..7 -> rows rr*8 .. rr*8+7

    f32x4 acc[9];
#pragma unroll
    for (int i = 0; i < 9; ++i) acc[i] = (f32x4){0.f, 0.f, 0.f, 0.f};

    float csum[4] = {0.f, 0.f, 0.f, 0.f};
    float sabs = 0.f;

    float4 g0, g1, g2, g3, g4, g5, g6, g7;   // asm-pinned staging registers

    auto issue = [&](int kt) {
        const char* a = (const char*)(xb + ((size_t)kt * KT + rr * 8) * FF + c * 4);
        asm volatile(
            "global_load_dwordx4 %0, %8, off\n\t"
            "global_load_dwordx4 %1, %8, off offset:512\n\t"
            "global_load_dwordx4 %2, %8, off offset:1024\n\t"
            "global_load_dwordx4 %3, %8, off offset:1536\n\t"
            "global_load_dwordx4 %4, %8, off offset:2048\n\t"
            "global_load_dwordx4 %5, %8, off offset:2560\n\t"
            "global_load_dwordx4 %6, %8, off offset:3072\n\t"
            "global_load_dwordx4 %7, %8, off offset:3584"
            : "=&v"(g0), "=&v"(g1), "=&v"(g2), "=&v"(g3),
              "=&v"(g4), "=&v"(g5), "=&v"(g6), "=&v"(g7)
            : "v"(a)
            : "memory");
    };

    auto drain = [&]() {
        asm volatile("s_waitcnt vmcnt(0)" ::: "memory");
        __builtin_amdgcn_sched_barrier(0);   // rule #18: no reg-op hoisting past the wait
    };

    // thread holds 8 t-rows x 4 f; per f: pack 8 bf16 -> one ds_write_b128
    auto convert = [&](int kt) {
        char* tb = &bufT[kt & 1][0];
#pragma unroll
        for (int j = 0; j < 4; ++j) {
            const float v0 = elem(g0, j), v1 = elem(g1, j), v2 = elem(g2, j),
                        v3 = elem(g3, j), v4 = elem(g4, j), v5 = elem(g5, j),
                        v6 = elem(g6, j), v7 = elem(g7, j);
            csum[j] += ((v0 + v1) + (v2 + v3)) + ((v4 + v5) + (v6 + v7));
            sabs += ((fabsf(v0) + fabsf(v1)) + (fabsf(v2) + fabsf(v3)))
                  + ((fabsf(v4) + fabsf(v5)) + (fabsf(v6) + fabsf(v7)));
            uint4 val;
            val.x = f2bf(v0) | (f2bf(v1) << 16);
            val.y = f2bf(v2) | (f2bf(v3) << 16);
            val.z = f2bf(v4) | (f2bf(v5) << 16);
            val.w = f2bf(v6) | (f2bf(v7) << 16);
            *(uint4*)(tb + (c * 4 + j) * TSTRIDE + rr * 16) = val;
        }
    };

    auto frag = [&](const char* tb, int ft, int ks) -> bf16x8_t {
        return *(const bf16x8_t*)(tb + (ft * 16 + m) * TSTRIDE + ks * 64 + h * 16);
    };

    auto domfma = [&](int buf) {
        const char* tb = &bufT[buf][0];
#pragma unroll
        for (int ks = 0; ks < 2; ++ks) {
#pragma unroll
            for (int i = 0; i < 9; ++i) {
                bf16x8_t a = frag(tb, TR[w][i], ks);
                bf16x8_t bb = frag(tb, TC[w][i], ks);
                acc[i] = __builtin_amdgcn_mfma_f32_16x16x32_bf16(a, bb, acc[i], 0, 0, 0);
            }
        }
    };

    // ---- prologue ----
    issue(0);
    drain();
    convert(0);
    asm volatile("s_waitcnt lgkmcnt(0)" ::: "memory");
    __builtin_amdgcn_s_barrier();
    __builtin_amdgcn_sched_barrier(0);

    // ---- main loop: 4 phases, one barrier each ----
    for (int p = 0; p < NKT; ++p) {
        if (p + 1 < NKT) issue(p + 1);
        domfma(p & 1);
        if (p + 1 < NKT) {
            drain();
            convert(p + 1);
            asm volatile("s_waitcnt lgkmcnt(0)" ::: "memory");
            __builtin_amdgcn_s_barrier();
            __builtin_amdgcn_sched_barrier(0);
        }
    }

    // ---- epilogue: plain stores of this wave's 9 tiles ----
    float* Pb = ws + P_OFF + (size_t)blockIdx.x * PART_FLOATS;
#pragma unroll
    for (int i = 0; i < 9; ++i) {
        const int tn = TT[w][i];
#pragma unroll
        for (int q = 0; q < 4; ++q)
            Pb[tn * TILE_ELEMS + (h * 4 + q) * 16 + m] = acc[i][q];
    }

    // ---- column sums: wave-pair fold, then cross-wave LDS fold, 128 atomics ----
#pragma unroll
    for (int j = 0; j < 4; ++j) {
        float t = csum[j] + __shfl_down(csum[j], 32, 64);
        if (lane < 32) csr[w][(lane & 31) * 4 + j] = t;
    }

    // ---- sum |x| ----
#pragma unroll
    for (int off = 32; off > 0; off >>= 1) sabs += __shfl_down(sabs, off, 64);
    if (lane == 0) redsa[w] = sabs;
    __syncthreads();
    if (tid < FF)
        atomicAdd(&ws[SUM0_OFF + b * FF + tid],
                  (csr[0][tid] + csr[1][tid]) + (csr[2][tid] + csr[3][tid]));
    if (tid == 0)
        atomicAdd(&ws[SABS_OFF], (redsa[0] + redsa[1]) + (redsa[2] + redsa[3]));
}

// ---------------------------------------------------------------------------
// Kernel 2: reduce the SPLIT per-chunk partials: R[b][e] = sum_s P[b*16+s][e]
// ---------------------------------------------------------------------------
__global__ __launch_bounds__(256) void reduce_kernel(float* __restrict__ ws)
{
    const int bb = blockIdx.x / NTILE_UP;                 // batch
    const int e  = (blockIdx.x % NTILE_UP) * 256 + threadIdx.x;
    const float* P = ws + P_OFF + (size_t)bb * SPLIT * PART_FLOATS + e;
    float acc = 0.f;
#pragma unroll
    for (int s = 0; s < SPLIT; ++s) acc += P[(size_t)s * PART_FLOATS];
    ws[R_OFF + (size_t)bb * PART_FLOATS + e] = acc;
}

// ---------------------------------------------------------------------------
// Kernel 3: per (b,f) mean and 1/std from R diagonal tiles.
// ---------------------------------------------------------------------------
__global__ void stats_kernel(float* __restrict__ ws)
{
    const int idx = blockIdx.x * blockDim.x + threadIdx.x;  // 0..8191
    const int b = idx >> 7, f = idx & 127;
    const float mean = ws[SUM0_OFF + idx] * (1.f / TN);
    const float s2d = ws[R_OFF + (size_t)b * PART_FLOATS
                         + (size_t)kRowBase[f >> 4] * TILE_ELEMS + (f & 15) * 17];
    const float var = s2d * (1.f / TN) - mean * mean;
    ws[MEAN_OFF + idx] = mean;
    ws[RSTD_OFF + idx] = rsqrtf(fmaxf(var, 1e-30f));
}

// ---------------------------------------------------------------------------
// Kernel 4: corr_avg_abs + strict upper-tri masked sum (reads compact R).
// ---------------------------------------------------------------------------
__global__ __launch_bounds__(256) void corr_kernel(float* __restrict__ ws)
{
    __shared__ float red[4];
    const int p = blockIdx.x * 256 + threadIdx.x;   // 0..16383
    const int f = p >> 7, g = p & 127;

    float v = 0.f;
    if (g > f) {
        const int tidx = kRowBase[f >> 4] + ((g >> 4) - (f >> 4));
        const size_t off = (size_t)tidx * TILE_ELEMS + (f & 15) * 16 + (g & 15);
        float accum = 0.f;
#pragma unroll 8
        for (int b = 0; b < BB; ++b) {
            const float s2 = ws[R_OFF + (size_t)b * PART_FLOATS + off];
            const float mf = ws[MEAN_OFF + b * FF + f];
            const float mg = ws[MEAN_OFF + b * FF + g];
            const float rf = ws[RSTD_OFF + b * FF + f];
            const float rg = ws[RSTD_OFF + b * FF + g];
            accum += (s2 * (1.f / TN) - mf * mg) * rf * rg;
        }
        v = fabsf(accum * (1.f / BB));
    }

#pragma unroll
    for (int off = 32; off > 0; off >>= 1) v += __shfl_down(v, off, 64);
    const int lane = threadIdx.x & 63, wid = threadIdx.x >> 6;
    if (lane == 0) red[wid] = v;
    __syncthreads();
    if (threadIdx.x == 0)
        atomicAdd(&ws[TRI_OFF], red[0] + red[1] + red[2] + red[3]);
}

// ---------------------------------------------------------------------------
// Kernel 5: write the 3 outputs.
// ---------------------------------------------------------------------------
__global__ void final_kernel(const float* __restrict__ ws, float* __restrict__ out)
{
    const float tri  = ws[TRI_OFF];
    const float sabs = ws[SABS_OFF];
    const float n_pairs = (float)(FF * (FF - 1) / 2);   // 8128
    out[0] = tri * (0.01f / n_pairs);
    out[1] = tri;
    out[2] = sabs * (1.f / FF);
}

extern "C" void kernel_launch(void* const* d_in, const int* in_sizes, int n_in,
                              void* d_out, int out_size, void* d_ws, size_t ws_size,
                              hipStream_t stream)
{
    const float* x = (const float*)d_in[0];
    float* out = (float*)d_out;
    float* ws = (float*)d_ws;

    // zero only the atomic-accumulation region
    (void)hipMemsetAsync(d_ws, 0, (size_t)ZERO_FLOATS * sizeof(float), stream);

    hipLaunchKernelGGL(cov_kernel,    dim3(NBLK), dim3(256), 0, stream, x, ws);
    hipLaunchKernelGGL(reduce_kernel, dim3(BB * NTILE_UP), dim3(256), 0, stream, ws);
    hipLaunchKernelGGL(stats_kernel,  dim3((BB * FF) / 256), dim3(256), 0, stream, ws);
    hipLaunchKernelGGL(corr_kernel,   dim3((FF * FF) / 256), dim3(256), 0, stream, ws);
    hipLaunchKernelGGL(final_kernel,  dim3(1), dim3(1), 0, stream, ws, out);
}